// Round 17
// baseline (254.869 us; speedup 1.0000x reference)
//
#include <hip/hip_runtime.h>

#define CHN 16
#define HID 128
#define NB 32
#define NH 128
#define NW 128
#define NPIX (NB*NH*NW)      // 524288
#define TPB 1024             // 16 waves/block; 2 blocks/CU co-resident, grid=512=2 WG/CU
#define WSTR 56              // W0s row stride: cols 0..47=W0, 48=b0, 49..55=0

typedef __attribute__((ext_vector_type(8))) short bf16x8;
typedef __attribute__((ext_vector_type(4))) float f32x4;
typedef __attribute__((ext_vector_type(4))) int i32x4;

// JAX threefry2x32 (20 rounds). Verified vs Random123 test vectors.
__host__ __device__ inline void threefry2x32(unsigned k0, unsigned k1,
                                             unsigned x0, unsigned x1,
                                             unsigned &o0, unsigned &o1) {
  unsigned ks2 = 0x1BD11BDAu ^ k0 ^ k1;
  unsigned v0 = x0 + k0, v1 = x1 + k1;
#define TF_R(r) { v0 += v1; v1 = (v1 << (r)) | (v1 >> (32-(r))); v1 ^= v0; }
  TF_R(13) TF_R(15) TF_R(26) TF_R(6)
  v0 += k1;  v1 += ks2 + 1u;
  TF_R(17) TF_R(29) TF_R(16) TF_R(24)
  v0 += ks2; v1 += k0 + 2u;
  TF_R(13) TF_R(15) TF_R(26) TF_R(6)
  v0 += k0;  v1 += k1 + 3u;
  TF_R(17) TF_R(29) TF_R(16) TF_R(24)
  v0 += k1;  v1 += ks2 + 4u;
  TF_R(13) TF_R(15) TF_R(26) TF_R(6)
  v0 += ks2; v1 += k0 + 5u;
#undef TF_R
  o0 = v0; o1 = v1;
}

// RNE f32->bf16 via compiler __bf16 (lowers to v_cvt_pk_bf16_f32 pairs)
__device__ inline unsigned short f2bf(float f) {
  return __builtin_bit_cast(unsigned short, (__bf16)f);
}
__device__ inline unsigned pk2(float lo, float hi) {
  return (unsigned)f2bf(lo) | ((unsigned)f2bf(hi) << 16);
}
__device__ inline bf16x8 cvt8(float4 a, float4 b) {
  i32x4 r;
  r[0] = (int)pk2(a.x, a.y); r[1] = (int)pk2(a.z, a.w);
  r[2] = (int)pk2(b.x, b.y); r[3] = (int)pk2(b.z, b.w);
  return __builtin_bit_cast(bf16x8, r);
}

// Kernel A (r15 structure @ 1024 threads): depth-first perceive -> y1/y2 to LDS;
// yc from L1 at fragment build -> MFMA MLP (W0 in LDS, bias at k=48) ->
// permlane transpose -> x_mid = x + dx*fire (ballot fire, T14 prefetch).
// LDS = W0s(14336) + y1s(32768) + y2s(32768) = 79872 B -> exactly 2 blocks/CU;
// grid=512 -> 2 WG/CU: whole kernel co-resident, zero tail. VGPR target 64
// (r11/r15/r16 all compiled to 64 under the same 128 cap).
__global__ __launch_bounds__(TPB, 4) void ca_step_a(
    const float* __restrict__ xin,
    const float* __restrict__ W0g,
    const float* __restrict__ b0g,
    const float* __restrict__ W1g,
    float* __restrict__ xmid,
    float* __restrict__ alphaOut,
    unsigned char* __restrict__ preLife,
    unsigned sk0, unsigned sk1)
{
  __shared__ __align__(16) short W0s[128 * WSTR];  // 14336 B
  __shared__ __align__(16) short y1s[TPB * 16];    // 32768 B
  __shared__ __align__(16) short y2s[TPB * 16];    // 32768 B

  const int tid = threadIdx.x;
  const int l = tid & 63, w = tid >> 6;
  const int lc = l & 15, lg = l >> 4;

  // ---- stage W0 (f32->bf16) + bias col 48 + zero pad 49..55 (waves 0-3) ----
  if (tid < 256) {
    const int o = tid >> 1;
    if ((tid & 1) == 0) {
#pragma unroll
      for (int k = 0; k < 24; k += 2)
        *(unsigned*)&W0s[o * WSTR + k] = pk2(W0g[o * 48 + k], W0g[o * 48 + k + 1]);
    } else {
#pragma unroll
      for (int k = 24; k < 48; k += 2)
        *(unsigned*)&W0s[o * WSTR + k] = pk2(W0g[o * 48 + k], W0g[o * 48 + k + 1]);
      *(unsigned*)&W0s[o * WSTR + 48] = (unsigned)f2bf(b0g[o]);   // (b0, 0)
      *(unsigned*)&W0s[o * WSTR + 50] = 0u;
      *(unsigned*)&W0s[o * WSTR + 52] = 0u;
      *(unsigned*)&W0s[o * WSTR + 54] = 0u;
    }
  }

  // ---- depth-first perceive (lane <-> pixel 1:1); yc not tracked ----
  const int pBase = blockIdx.x * TPB;
  const int p = pBase + tid;
  const int j = p & (NW - 1);
  const int i0 = (p >> 7) & (NH - 1);

  float y1[CHN], y2[CHN];
#pragma unroll
  for (int c = 0; c < CHN; ++c) { y1[c] = 0.f; y2[c] = 0.f; }
  float amax = -1e30f;

#pragma unroll
  for (int dh = 0; dh < 3; ++dh) {
#pragma unroll
    for (int dw = 0; dw < 3; ++dw) {
      const int ii = i0 + dh - 1, jj = j + dw - 1;
      if ((unsigned)ii < NH && (unsigned)jj < NW) {
        const float* src = xin + ((size_t)p + (size_t)(dh - 1) * NW + (dw - 1)) * CHN;
        float v[CHN];
        *(float4*)(v)      = *(const float4*)(src);
        *(float4*)(v + 4)  = *(const float4*)(src + 4);
        *(float4*)(v + 8)  = *(const float4*)(src + 8);
        *(float4*)(v + 12) = *(const float4*)(src + 12);
        amax = fmaxf(amax, v[3]);
        const float gh = (dh == 0) ? -1.f : ((dh == 2) ? 1.f : 0.f);
        const float sh = (dh == 1) ? 2.f : 1.f;
        const float gw = (dw == 0) ? -1.f : ((dw == 2) ? 1.f : 0.f);
        const float sw = (dw == 1) ? 2.f : 1.f;
        const float g1 = gh * sw * 0.125f;
        const float g2 = sh * gw * 0.125f;
        if (g1 != 0.f) {
#pragma unroll
          for (int c = 0; c < CHN; ++c) y1[c] = fmaf(g1, v[c], y1[c]);
        }
        if (g2 != 0.f) {
#pragma unroll
          for (int c = 0; c < CHN; ++c) y2[c] = fmaf(g2, v[c], y2[c]);
        }
      }
    }
  }

  preLife[p] = (amax > 0.1f) ? (unsigned char)1 : (unsigned char)0;
  unsigned long long fmask;
  {
    unsigned b1_, b2_;
    threefry2x32(sk0, sk1, 0u, (unsigned)p, b1_, b2_);   // partitionable: bits = v0^v1
    fmask = __ballot(((b1_ ^ b2_) & 0x80000000u) == 0u);
  }

  // ---- y1/y2 to LDS (wave-local, in-order DS) ----
  {
    i32x4 u;
    u[0] = (int)pk2(y1[0], y1[1]);   u[1] = (int)pk2(y1[2], y1[3]);
    u[2] = (int)pk2(y1[4], y1[5]);   u[3] = (int)pk2(y1[6], y1[7]);
    *(i32x4*)&y1s[tid * 16] = u;
    u[0] = (int)pk2(y1[8], y1[9]);   u[1] = (int)pk2(y1[10], y1[11]);
    u[2] = (int)pk2(y1[12], y1[13]); u[3] = (int)pk2(y1[14], y1[15]);
    *(i32x4*)&y1s[tid * 16 + 8] = u;
    u[0] = (int)pk2(y2[0], y2[1]);   u[1] = (int)pk2(y2[2], y2[3]);
    u[2] = (int)pk2(y2[4], y2[5]);   u[3] = (int)pk2(y2[6], y2[7]);
    *(i32x4*)&y2s[tid * 16] = u;
    u[0] = (int)pk2(y2[8], y2[9]);   u[1] = (int)pk2(y2[10], y2[11]);
    u[2] = (int)pk2(y2[12], y2[13]); u[3] = (int)pk2(y2[14], y2[15]);
    *(i32x4*)&y2s[tid * 16 + 8] = u;
  }

  // ---- W1 A-fragments from global (row c=lc, k=kt*32+lg*8..+8) ----
  bf16x8 W1f[4];
#pragma unroll
  for (int kt = 0; kt < 4; ++kt) {
    const float* src = &W1g[lc * HID + kt * 32 + (lg << 3)];
    W1f[kt] = cvt8(*(const float4*)(src), *(const float4*)(src + 4));
  }

  __syncthreads();   // W0s visible (y1s/y2s wave-local)

  const bf16x8 zero8 = {};
  bf16x8 one8 = {};
  one8[0] = (short)0x3F80;            // bf16 1.0 at k=48 -> picks up bias col

  // Y B-fragments: Yf0 = {yc = bf16(x) from L1 (lg0/1) | y1 from LDS (lg2/3)};
  //                Yf1 = {y2 from LDS (lg0/1) | bias 1.0 (lg2) | 0 (lg3)}
  bf16x8 Yf[4][2];
#pragma unroll
  for (int m = 0; m < 4; ++m) {
    const int q = (w << 6) + (m << 4) + lc;              // block-local pixel
    const int q16 = q * 16;
    if (lg < 2) {
      const float* s = &xin[(size_t)(pBase + q) * CHN + ((lg & 1) << 3)];
      Yf[m][0] = cvt8(*(const float4*)s, *(const float4*)(s + 4));
      Yf[m][1] = *(const bf16x8*)&y2s[q16 + ((lg & 1) << 3)];
    } else {
      Yf[m][0] = *(const bf16x8*)&y1s[q16 + ((lg & 1) << 3)];
      Yf[m][1] = (lg == 2) ? one8 : zero8;
    }
  }

  // T14: prefetch epilogue x reloads (L1-hot) so latency hides under MFMAs
  float4 xpre[4];
#pragma unroll
  for (int m = 0; m < 4; ++m) {
    const int pp = pBase + (w << 6) + (m << 4) + lc;
    xpre[m] = *(const float4*)&xin[(size_t)pp * CHN + (lg << 2)];
  }

  f32x4 dxacc[4];
#pragma unroll
  for (int m = 0; m < 4; ++m) dxacc[m] = (f32x4){0.f, 0.f, 0.f, 0.f};

#pragma unroll
  for (int kt_o = 0; kt_o < 4; ++kt_o) {
    bf16x8 Wf0[2], Wf1[2];
#pragma unroll
    for (int th = 0; th < 2; ++th) {
      const int row = ((((kt_o << 1) + th) << 4) + lc) * WSTR;
      Wf0[th] = *(const bf16x8*)&W0s[row + (lg << 3)];
      Wf1[th] = (lg < 3) ? *(const bf16x8*)&W0s[row + 32 + (lg << 3)] : zero8;
    }
#pragma unroll
    for (int m = 0; m < 4; ++m) {
      f32x4 a0 = __builtin_amdgcn_mfma_f32_16x16x32_bf16(
          Wf0[0], Yf[m][0], (f32x4){0.f, 0.f, 0.f, 0.f}, 0, 0, 0);
      a0 = __builtin_amdgcn_mfma_f32_16x16x32_bf16(Wf1[0], Yf[m][1], a0, 0, 0, 0);
      f32x4 a1 = __builtin_amdgcn_mfma_f32_16x16x32_bf16(
          Wf0[1], Yf[m][0], (f32x4){0.f, 0.f, 0.f, 0.f}, 0, 0, 0);
      a1 = __builtin_amdgcn_mfma_f32_16x16x32_bf16(Wf1[1], Yf[m][1], a1, 0, 0, 0);
      // relu + pack
      unsigned xa = pk2(fmaxf(a0[0], 0.f), fmaxf(a0[1], 0.f));
      unsigned xb = pk2(fmaxf(a0[2], 0.f), fmaxf(a0[3], 0.f));
      unsigned ya = pk2(fmaxf(a1[0], 0.f), fmaxf(a1[1], 0.f));
      unsigned yb = pk2(fmaxf(a1[2], 0.f), fmaxf(a1[3], 0.f));
      // lg-group transpose (VALU): [a0..a3],[b0..b3] -> [a0,a2,b0,b2],[a1,a3,b1,b3]
      asm("v_permlane32_swap_b32 %0, %1" : "+v"(xa), "+v"(ya));
      asm("v_permlane32_swap_b32 %0, %1" : "+v"(xb), "+v"(yb));
      asm("v_permlane16_swap_b32 %0, %1" : "+v"(xa), "+v"(ya));
      asm("v_permlane16_swap_b32 %0, %1" : "+v"(xb), "+v"(yb));
      i32x4 bfr;
      bfr[0] = (int)xa;   // k lg*8+0,1
      bfr[1] = (int)xb;   // k lg*8+2,3
      bfr[2] = (int)ya;   // k lg*8+4,5
      bfr[3] = (int)yb;   // k lg*8+6,7
      dxacc[m] = __builtin_amdgcn_mfma_f32_16x16x32_bf16(
          W1f[kt_o], __builtin_bit_cast(bf16x8, bfr), dxacc[m], 0, 0, 0);
    }
  }

  // ---- epilogue: dx^T C-layout (row c=lg*4+r, col px=m*16+lc) -> float4/lane ----
#pragma unroll
  for (int m = 0; m < 4; ++m) {
    const int q = (m << 4) + lc;               // lane holding pixel's fire bit
    const int pp = pBase + (w << 6) + q;
    const float f = (float)((fmask >> q) & 1ull);
    float4 xm;
    xm.x = fmaf(dxacc[m][0], f, xpre[m].x);
    xm.y = fmaf(dxacc[m][1], f, xpre[m].y);
    xm.z = fmaf(dxacc[m][2], f, xpre[m].z);
    xm.w = fmaf(dxacc[m][3], f, xpre[m].w);
    *(float4*)&xmid[(size_t)pp * CHN + (lg << 2)] = xm;
    if (lg == 0) alphaOut[pp] = xm.w;   // channel 3
  }
}

// Kernel B: post_life = 3x3 maxpool(alpha) > 0.1; x = x_mid * (pre & post)
__global__ __launch_bounds__(256) void ca_step_b(
    const float* __restrict__ xmid,
    const float* __restrict__ alphaIn,
    const unsigned char* __restrict__ preLife,
    float* __restrict__ xout)
{
  const int p = blockIdx.x * 256 + threadIdx.x;
  const int j = p & (NW - 1);
  const int i = (p >> 7) & (NH - 1);
  float pmax = -1e30f;
#pragma unroll
  for (int dh = 0; dh < 3; ++dh) {
#pragma unroll
    for (int dw = 0; dw < 3; ++dw) {
      const int ii = i + dh - 1, jj = j + dw - 1;
      if ((unsigned)ii < NH && (unsigned)jj < NW)
        pmax = fmaxf(pmax, alphaIn[p + (dh - 1) * NW + (dw - 1)]);
    }
  }
  const float m = ((pmax > 0.1f) && (preLife[p] != 0)) ? 1.f : 0.f;
  const float* src = xmid + (size_t)p * CHN;
  float4 a = *(const float4*)(src);
  float4 b = *(const float4*)(src + 4);
  float4 c = *(const float4*)(src + 8);
  float4 d = *(const float4*)(src + 12);
  a.x *= m; a.y *= m; a.z *= m; a.w *= m;
  b.x *= m; b.y *= m; b.z *= m; b.w *= m;
  c.x *= m; c.y *= m; c.z *= m; c.w *= m;
  d.x *= m; d.y *= m; d.z *= m; d.w *= m;
  float* dst = xout + (size_t)p * CHN;
  *(float4*)(dst)      = a;
  *(float4*)(dst + 4)  = b;
  *(float4*)(dst + 8)  = c;
  *(float4*)(dst + 12) = d;
}

extern "C" void kernel_launch(void* const* d_in, const int* in_sizes, int n_in,
                              void* d_out, int out_size, void* d_ws, size_t ws_size,
                              hipStream_t stream) {
  const float* x  = (const float*)d_in[0];
  const float* W0 = (const float*)d_in[1];
  const float* b0 = (const float*)d_in[2];
  const float* W1 = (const float*)d_in[3];
  float* out = (float*)d_out;

  char* ws = (char*)d_ws;
  float* X = (float*)ws;                                        // NPIX*16 f32
  float* alphaB = (float*)(ws + (size_t)NPIX * CHN * 4);        // NPIX f32
  unsigned char* pl = (unsigned char*)(ws + (size_t)NPIX * CHN * 4 + (size_t)NPIX * 4);

  const dim3 gridA(NPIX / TPB), blockA(TPB);
  const dim3 gridB(NPIX / 256), blockB(256);
  const int STEPS = 4;
  for (int s = 0; s < STEPS; ++s) {
    unsigned k0, k1;
    threefry2x32(0u, 42u, 0u, (unsigned)s, k0, k1);   // fold_in(key(42), s)
    const float* src = (s == 0) ? x : X;
    ca_step_a<<<gridA, blockA, 0, stream>>>(src, W0, b0, W1, out, alphaB, pl, k0, k1);
    float* dst = (s == STEPS - 1) ? out : X;
    ca_step_b<<<gridB, blockB, 0, stream>>>(out, alphaB, pl, dst);
  }
}

// Round 19
// 213.524 us; speedup vs baseline: 1.1936x; 1.1936x over previous
//
#include <hip/hip_runtime.h>

#define CHN 16
#define HID 128
#define NB 32
#define NH 128
#define NW 128
#define NPIX (NB*NH*NW)      // 524288
#define TPB 256
#define HW2 66               // halo width
#define HH2 6                // halo height
#define WSTR 56              // W0s row stride: 0..47=W0, 48=b0, 49..55=0

typedef __attribute__((ext_vector_type(8))) short bf16x8;
typedef __attribute__((ext_vector_type(4))) float f32x4;
typedef __attribute__((ext_vector_type(4))) int i32x4;

// JAX threefry2x32 (20 rounds). Verified vs Random123 test vectors.
__host__ __device__ inline void threefry2x32(unsigned k0, unsigned k1,
                                             unsigned x0, unsigned x1,
                                             unsigned &o0, unsigned &o1) {
  unsigned ks2 = 0x1BD11BDAu ^ k0 ^ k1;
  unsigned v0 = x0 + k0, v1 = x1 + k1;
#define TF_R(r) { v0 += v1; v1 = (v1 << (r)) | (v1 >> (32-(r))); v1 ^= v0; }
  TF_R(13) TF_R(15) TF_R(26) TF_R(6)
  v0 += k1;  v1 += ks2 + 1u;
  TF_R(17) TF_R(29) TF_R(16) TF_R(24)
  v0 += ks2; v1 += k0 + 2u;
  TF_R(13) TF_R(15) TF_R(26) TF_R(6)
  v0 += k0;  v1 += k1 + 3u;
  TF_R(17) TF_R(29) TF_R(16) TF_R(24)
  v0 += k1;  v1 += ks2 + 4u;
  TF_R(13) TF_R(15) TF_R(26) TF_R(6)
  v0 += ks2; v1 += k0 + 5u;
#undef TF_R
  o0 = v0; o1 = v1;
}

// RNE f32->bf16 via compiler __bf16 (lowers to v_cvt_pk_bf16_f32 pairs)
__device__ inline unsigned short f2bf(float f) {
  return __builtin_bit_cast(unsigned short, (__bf16)f);
}
__device__ inline unsigned pk2(float lo, float hi) {
  return (unsigned)f2bf(lo) | ((unsigned)f2bf(hi) << 16);
}
__device__ inline bf16x8 cvt8(float4 a, float4 b) {
  i32x4 r;
  r[0] = (int)pk2(a.x, a.y); r[1] = (int)pk2(a.z, a.w);
  r[2] = (int)pk2(b.x, b.y); r[3] = (int)pk2(b.z, b.w);
  return __builtin_bit_cast(bf16x8, r);
}
__device__ inline float bflo(int u) {        // low bf16 -> f32
  return __builtin_bit_cast(float, (unsigned)u << 16);
}
__device__ inline float bfhi(int u) {        // high bf16 -> f32
  return __builtin_bit_cast(float, (unsigned)u & 0xFFFF0000u);
}

// Kernel A [r12-verified numerics, absmax 0.03125]: stage 66x6 bf16 x-tile +
// EXACT f32 alpha-tile; build Yf fragments directly from tile (raw read for yc,
// 6-tap stencil for y1/y2 computed per-fragment); MFMA MLP; x_mid = x+dx*fire.
// LDS = xT(12672) + aT(1584) + W0s(14336) = 28592 B.
// launch_bounds(,2): 256-VGPR budget -> r12's (,5) spill (VGPR 48 + 180MB
// scratch) is structurally impossible; runtime packs blocks by actual usage.
__global__ __launch_bounds__(TPB, 2) void ca_step_a(
    const float* __restrict__ xin,
    const float* __restrict__ W0g,
    const float* __restrict__ b0g,
    const float* __restrict__ W1g,
    float* __restrict__ xmid,
    float* __restrict__ alphaOut,
    unsigned char* __restrict__ preLife,
    unsigned sk0, unsigned sk1)
{
  __shared__ __align__(16) short xT[HH2 * HW2 * CHN];  // bf16 x tile (+halo)
  __shared__ float aT[HH2 * HW2];                      // EXACT f32 alpha tile
  __shared__ __align__(16) short W0s[128 * WSTR];

  const int tid = threadIdx.x;
  const int w = tid >> 6, l = tid & 63;
  const int lc = l & 15, lg = l >> 4;

  const int bb = blockIdx.x >> 6;           // batch
  const int t6 = blockIdx.x & 63;
  const int R0 = (t6 >> 1) << 2;            // tile row base
  const int C0 = (t6 & 1) << 6;             // tile col base

  // ---- stage W0 (f32->bf16) + bias col 48 + zero pad ----
  {
    const int o = tid >> 1;
    if ((tid & 1) == 0) {
#pragma unroll
      for (int k = 0; k < 24; k += 2)
        *(unsigned*)&W0s[o * WSTR + k] = pk2(W0g[o * 48 + k], W0g[o * 48 + k + 1]);
    } else {
#pragma unroll
      for (int k = 24; k < 48; k += 2)
        *(unsigned*)&W0s[o * WSTR + k] = pk2(W0g[o * 48 + k], W0g[o * 48 + k + 1]);
      *(unsigned*)&W0s[o * WSTR + 48] = (unsigned)f2bf(b0g[o]);   // (b0, 0)
      *(unsigned*)&W0s[o * WSTR + 50] = 0u;
      *(unsigned*)&W0s[o * WSTR + 52] = 0u;
      *(unsigned*)&W0s[o * WSTR + 54] = 0u;
    }
  }

  // ---- stage x halo tile (bf16) + alpha tile (f32) ----
  for (int h = tid; h < HH2 * HW2; h += TPB) {
    const int r = h / HW2, c = h - r * HW2;
    const int R = R0 + r - 1, C = C0 + c - 1;
    float4 v0, v1, v2, v3;
    float av;
    if ((unsigned)R < NH && (unsigned)C < NW) {
      const float* s = xin + (((size_t)bb * NH + R) * NW + C) * CHN;
      v0 = *(const float4*)(s);
      v1 = *(const float4*)(s + 4);
      v2 = *(const float4*)(s + 8);
      v3 = *(const float4*)(s + 12);
      av = v0.w;                            // exact f32 alpha (ch 3)
    } else {
      v0 = v1 = v2 = v3 = (float4){0.f, 0.f, 0.f, 0.f};
      av = -1e30f;                          // -inf pad for max-pool
    }
    i32x4 u;
    u[0] = (int)pk2(v0.x, v0.y); u[1] = (int)pk2(v0.z, v0.w);
    u[2] = (int)pk2(v1.x, v1.y); u[3] = (int)pk2(v1.z, v1.w);
    *(i32x4*)&xT[h * CHN] = u;
    u[0] = (int)pk2(v2.x, v2.y); u[1] = (int)pk2(v2.z, v2.w);
    u[2] = (int)pk2(v3.x, v3.y); u[3] = (int)pk2(v3.z, v3.w);
    *(i32x4*)&xT[h * CHN + 8] = u;
    aT[h] = av;
  }

  // ---- fire mask (own pixel = row R0+w, col C0+l) ----
  const int p = (bb * NH + R0 + w) * NW + C0 + l;
  unsigned long long fmask;
  {
    unsigned b1_, b2_;
    threefry2x32(sk0, sk1, 0u, (unsigned)p, b1_, b2_);   // partitionable: bits = v0^v1
    fmask = __ballot(((b1_ ^ b2_) & 0x80000000u) == 0u);
  }

  __syncthreads();   // xT/aT/W0s visible

  // ---- pre_life from EXACT f32 alpha tile (own pixel at (w+1, l+1)) ----
  {
    float am = -1e30f;
#pragma unroll
    for (int dr = 0; dr < 3; ++dr)
#pragma unroll
      for (int dc = 0; dc < 3; ++dc)
        am = fmaxf(am, aT[(w + dr) * HW2 + (l + dc)]);
    preLife[p] = (am > 0.1f) ? (unsigned char)1 : (unsigned char)0;
  }

  // ---- build Yf fragments directly from xT ----
  // lane (lc,lg), tile m: pixel col q=m*16+lc of row w. Yf0: lg0/1 = yc ch0-7/8-15
  // (raw read); lg2/3 = y1 ch0-7/8-15 (H-grad stencil). Yf1: lg0/1 = y2 (W-grad);
  // lg2 = bias 1.0 at k=48; lg3 = zero.
  const bf16x8 zero8 = {};
  bf16x8 one8 = {};
  one8[0] = (short)0x3F80;
  const int choff = (lg & 1) << 3;
  const bool gH = (lg >= 2);
  const int sA = gH ? HW2 * CHN : CHN;     // shorts: ±row for y1, ±col for y2
  const int sB = gH ? CHN : HW2 * CHN;     // sweep axis

  bf16x8 Yf[4][2];
#pragma unroll
  for (int m = 0; m < 4; ++m) {
    const int q = (m << 4) + lc;
    const int base = ((w + 1) * HW2 + (q + 1)) * CHN + choff;
    const bf16x8 raw = *(const bf16x8*)&xT[base];
    const i32x4 M0 = *(const i32x4*)&xT[base - sA - sB];
    const i32x4 M1 = *(const i32x4*)&xT[base - sA];
    const i32x4 M2 = *(const i32x4*)&xT[base - sA + sB];
    const i32x4 P0 = *(const i32x4*)&xT[base + sA - sB];
    const i32x4 P1 = *(const i32x4*)&xT[base + sA];
    const i32x4 P2 = *(const i32x4*)&xT[base + sA + sB];
    i32x4 res;
#pragma unroll
    for (int k = 0; k < 4; ++k) {
      const float pl = fmaf(2.f, bflo(P1[k]), bflo(P0[k])) + bflo(P2[k]);
      const float ml = fmaf(2.f, bflo(M1[k]), bflo(M0[k])) + bflo(M2[k]);
      const float ph = fmaf(2.f, bfhi(P1[k]), bfhi(P0[k])) + bfhi(P2[k]);
      const float mh = fmaf(2.f, bfhi(M1[k]), bfhi(M0[k])) + bfhi(M2[k]);
      res[k] = (int)pk2((pl - ml) * 0.125f, (ph - mh) * 0.125f);
    }
    const bf16x8 st = __builtin_bit_cast(bf16x8, res);
    Yf[m][0] = gH ? st : raw;
    Yf[m][1] = gH ? ((lg == 2) ? one8 : zero8) : st;
  }

  // ---- W1 A-fragments from global (row c=lc, k=kt*32+lg*8..+8) ----
  bf16x8 W1f[4];
#pragma unroll
  for (int kt = 0; kt < 4; ++kt) {
    const float* src = &W1g[lc * HID + kt * 32 + (lg << 3)];
    W1f[kt] = cvt8(*(const float4*)(src), *(const float4*)(src + 4));
  }

  f32x4 dxacc[4];
#pragma unroll
  for (int m = 0; m < 4; ++m) dxacc[m] = (f32x4){0.f, 0.f, 0.f, 0.f};

#pragma unroll
  for (int kt_o = 0; kt_o < 4; ++kt_o) {
    bf16x8 Wf0[2], Wf1[2];
#pragma unroll
    for (int th = 0; th < 2; ++th) {
      const int row = ((((kt_o << 1) + th) << 4) + lc) * WSTR;
      Wf0[th] = *(const bf16x8*)&W0s[row + (lg << 3)];
      Wf1[th] = (lg < 3) ? *(const bf16x8*)&W0s[row + 32 + (lg << 3)] : zero8;
    }
#pragma unroll
    for (int m = 0; m < 4; ++m) {
      f32x4 a0 = __builtin_amdgcn_mfma_f32_16x16x32_bf16(
          Wf0[0], Yf[m][0], (f32x4){0.f, 0.f, 0.f, 0.f}, 0, 0, 0);
      a0 = __builtin_amdgcn_mfma_f32_16x16x32_bf16(Wf1[0], Yf[m][1], a0, 0, 0, 0);
      f32x4 a1 = __builtin_amdgcn_mfma_f32_16x16x32_bf16(
          Wf0[1], Yf[m][0], (f32x4){0.f, 0.f, 0.f, 0.f}, 0, 0, 0);
      a1 = __builtin_amdgcn_mfma_f32_16x16x32_bf16(Wf1[1], Yf[m][1], a1, 0, 0, 0);
      unsigned xa = pk2(fmaxf(a0[0], 0.f), fmaxf(a0[1], 0.f));
      unsigned xb = pk2(fmaxf(a0[2], 0.f), fmaxf(a0[3], 0.f));
      unsigned ya = pk2(fmaxf(a1[0], 0.f), fmaxf(a1[1], 0.f));
      unsigned yb = pk2(fmaxf(a1[2], 0.f), fmaxf(a1[3], 0.f));
      asm("v_permlane32_swap_b32 %0, %1" : "+v"(xa), "+v"(ya));
      asm("v_permlane32_swap_b32 %0, %1" : "+v"(xb), "+v"(yb));
      asm("v_permlane16_swap_b32 %0, %1" : "+v"(xa), "+v"(ya));
      asm("v_permlane16_swap_b32 %0, %1" : "+v"(xb), "+v"(yb));
      i32x4 bfr;
      bfr[0] = (int)xa; bfr[1] = (int)xb; bfr[2] = (int)ya; bfr[3] = (int)yb;
      dxacc[m] = __builtin_amdgcn_mfma_f32_16x16x32_bf16(
          W1f[kt_o], __builtin_bit_cast(bf16x8, bfr), dxacc[m], 0, 0, 0);
    }
  }

  // ---- epilogue: pixel (row R0+w, col C0+q), channels lg*4..+4 ----
#pragma unroll
  for (int m = 0; m < 4; ++m) {
    const int q = (m << 4) + lc;
    const int P = (bb * NH + R0 + w) * NW + C0 + q;
    const float f = (float)((fmask >> q) & 1ull);
    const float* src = &xin[(size_t)P * CHN + (lg << 2)];   // exact f32 residual
    float4 xc = *(const float4*)src;
    float4 xm;
    xm.x = fmaf(dxacc[m][0], f, xc.x);
    xm.y = fmaf(dxacc[m][1], f, xc.y);
    xm.z = fmaf(dxacc[m][2], f, xc.z);
    xm.w = fmaf(dxacc[m][3], f, xc.w);
    *(float4*)&xmid[(size_t)P * CHN + (lg << 2)] = xm;
    if (lg == 0) alphaOut[P] = xm.w;   // channel 3
  }
}

// Kernel B: post_life = 3x3 maxpool(alpha) > 0.1; x = x_mid * (pre & post)
__global__ __launch_bounds__(TPB) void ca_step_b(
    const float* __restrict__ xmid,
    const float* __restrict__ alphaIn,
    const unsigned char* __restrict__ preLife,
    float* __restrict__ xout)
{
  const int p = blockIdx.x * TPB + threadIdx.x;
  const int j = p & (NW - 1);
  const int i = (p >> 7) & (NH - 1);
  float pmax = -1e30f;
#pragma unroll
  for (int dh = 0; dh < 3; ++dh) {
#pragma unroll
    for (int dw = 0; dw < 3; ++dw) {
      const int ii = i + dh - 1, jj = j + dw - 1;
      if ((unsigned)ii < NH && (unsigned)jj < NW)
        pmax = fmaxf(pmax, alphaIn[p + (dh - 1) * NW + (dw - 1)]);
    }
  }
  const float m = ((pmax > 0.1f) && (preLife[p] != 0)) ? 1.f : 0.f;
  const float* src = xmid + (size_t)p * CHN;
  float4 a = *(const float4*)(src);
  float4 b = *(const float4*)(src + 4);
  float4 c = *(const float4*)(src + 8);
  float4 d = *(const float4*)(src + 12);
  a.x *= m; a.y *= m; a.z *= m; a.w *= m;
  b.x *= m; b.y *= m; b.z *= m; b.w *= m;
  c.x *= m; c.y *= m; c.z *= m; c.w *= m;
  d.x *= m; d.y *= m; d.z *= m; d.w *= m;
  float* dst = xout + (size_t)p * CHN;
  *(float4*)(dst)      = a;
  *(float4*)(dst + 4)  = b;
  *(float4*)(dst + 8)  = c;
  *(float4*)(dst + 12) = d;
}

extern "C" void kernel_launch(void* const* d_in, const int* in_sizes, int n_in,
                              void* d_out, int out_size, void* d_ws, size_t ws_size,
                              hipStream_t stream) {
  const float* x  = (const float*)d_in[0];
  const float* W0 = (const float*)d_in[1];
  const float* b0 = (const float*)d_in[2];
  const float* W1 = (const float*)d_in[3];
  float* out = (float*)d_out;

  char* ws = (char*)d_ws;
  float* X = (float*)ws;                                        // NPIX*16 f32
  float* alphaB = (float*)(ws + (size_t)NPIX * CHN * 4);        // NPIX f32
  unsigned char* pl = (unsigned char*)(ws + (size_t)NPIX * CHN * 4 + (size_t)NPIX * 4);

  const dim3 grid(NPIX / TPB), block(TPB);
  const int STEPS = 4;
  for (int s = 0; s < STEPS; ++s) {
    unsigned k0, k1;
    threefry2x32(0u, 42u, 0u, (unsigned)s, k0, k1);   // fold_in(key(42), s)
    const float* src = (s == 0) ? x : X;
    ca_step_a<<<grid, block, 0, stream>>>(src, W0, b0, W1, out, alphaB, pl, k0, k1);
    float* dst = (s == STEPS - 1) ? out : X;
    ca_step_b<<<grid, block, 0, stream>>>(out, alphaB, pl, dst);
  }
}

// Round 21
// 192.982 us; speedup vs baseline: 1.3207x; 1.1064x over previous
//
#include <hip/hip_runtime.h>

#define CHN 16
#define HID 128
#define NB 32
#define NH 128
#define NW 128
#define NPIX (NB*NH*NW)      // 524288
#define TPB 256
#define HW2 66               // halo width (x tile)
#define HH2 6                // halo height (x tile)
#define AW2 68               // alpha halo width (+2)
#define AH2 8                // alpha halo height (+2)
#define WSTR 56              // W0s row stride: 0..47=W0, 48=b0, 49..55=0

typedef __attribute__((ext_vector_type(8))) short bf16x8;
typedef __attribute__((ext_vector_type(4))) float f32x4;
typedef __attribute__((ext_vector_type(4))) int i32x4;

// JAX threefry2x32 (20 rounds). Verified vs Random123 test vectors.
__host__ __device__ inline void threefry2x32(unsigned k0, unsigned k1,
                                             unsigned x0, unsigned x1,
                                             unsigned &o0, unsigned &o1) {
  unsigned ks2 = 0x1BD11BDAu ^ k0 ^ k1;
  unsigned v0 = x0 + k0, v1 = x1 + k1;
#define TF_R(r) { v0 += v1; v1 = (v1 << (r)) | (v1 >> (32-(r))); v1 ^= v0; }
  TF_R(13) TF_R(15) TF_R(26) TF_R(6)
  v0 += k1;  v1 += ks2 + 1u;
  TF_R(17) TF_R(29) TF_R(16) TF_R(24)
  v0 += ks2; v1 += k0 + 2u;
  TF_R(13) TF_R(15) TF_R(26) TF_R(6)
  v0 += k0;  v1 += k1 + 3u;
  TF_R(17) TF_R(29) TF_R(16) TF_R(24)
  v0 += k1;  v1 += ks2 + 4u;
  TF_R(13) TF_R(15) TF_R(26) TF_R(6)
  v0 += ks2; v1 += k0 + 5u;
#undef TF_R
  o0 = v0; o1 = v1;
}

__device__ inline unsigned short f2bf(float f) {
  return __builtin_bit_cast(unsigned short, (__bf16)f);
}
__device__ inline unsigned pk2(float lo, float hi) {
  return (unsigned)f2bf(lo) | ((unsigned)f2bf(hi) << 16);
}
__device__ inline bf16x8 cvt8(float4 a, float4 b) {
  i32x4 r;
  r[0] = (int)pk2(a.x, a.y); r[1] = (int)pk2(a.z, a.w);
  r[2] = (int)pk2(b.x, b.y); r[3] = (int)pk2(b.z, b.w);
  return __builtin_bit_cast(bf16x8, r);
}
__device__ inline float bflo(int u) {
  return __builtin_bit_cast(float, (unsigned)u << 16);
}
__device__ inline float bfhi(int u) {
  return __builtin_bit_cast(float, (unsigned)u & 0xFFFF0000u);
}

// ---- shared MFMA core (r19-verified): consumes xT/aT/W0s, produces xmid+pl ----
// STAGE_MASK=0: plain staging from xin (step 0). STAGE_MASK=1: staging applies
// life = plIn & (3x3 pool of xprev alpha) — fuses step_b of the PREVIOUS step.
template <int STAGE_MASK>
__device__ __forceinline__ void ca_core(
    const float* __restrict__ xprev,
    const unsigned char* __restrict__ plIn,
    const float* __restrict__ W0g,
    const float* __restrict__ b0g,
    const float* __restrict__ W1g,
    float* __restrict__ xmid,
    unsigned char* __restrict__ plOut,
    unsigned sk0, unsigned sk1,
    short* W0s, short* xT, float* aT, float* aT2, unsigned char* lifeB)
{
  const int tid = threadIdx.x;
  const int w = tid >> 6, l = tid & 63;
  const int lc = l & 15, lg = l >> 4;

  const int bb = blockIdx.x >> 6;
  const int t6 = blockIdx.x & 63;
  const int R0 = (t6 >> 1) << 2;
  const int C0 = (t6 & 1) << 6;

  // ---- stage W0 (f32->bf16) + bias col 48 + zero pad ----
  {
    const int o = tid >> 1;
    if ((tid & 1) == 0) {
#pragma unroll
      for (int k = 0; k < 24; k += 2)
        *(unsigned*)&W0s[o * WSTR + k] = pk2(W0g[o * 48 + k], W0g[o * 48 + k + 1]);
    } else {
#pragma unroll
      for (int k = 24; k < 48; k += 2)
        *(unsigned*)&W0s[o * WSTR + k] = pk2(W0g[o * 48 + k], W0g[o * 48 + k + 1]);
      *(unsigned*)&W0s[o * WSTR + 48] = (unsigned)f2bf(b0g[o]);
      *(unsigned*)&W0s[o * WSTR + 50] = 0u;
      *(unsigned*)&W0s[o * WSTR + 52] = 0u;
      *(unsigned*)&W0s[o * WSTR + 54] = 0u;
    }
  }

  if (STAGE_MASK) {
    // stage raw xprev alpha (+2 halo) for the fused post-life pool
    for (int h2 = tid; h2 < AH2 * AW2; h2 += TPB) {
      const int r2 = h2 / AW2, c2 = h2 - r2 * AW2;
      const int Rg = R0 + r2 - 2, Cg = C0 + c2 - 2;
      aT2[h2] = ((unsigned)Rg < NH && (unsigned)Cg < NW)
          ? xprev[(((size_t)bb * NH + Rg) * NW + Cg) * CHN + 3] : -1e30f;
    }
    __syncthreads();   // aT2 visible before pooling in x-staging
  }

  // ---- stage x halo tile (bf16, masked if STAGE_MASK) + alpha tile (f32) ----
  for (int h = tid; h < HH2 * HW2; h += TPB) {
    const int r = h / HW2, c = h - r * HW2;
    const int R = R0 + r - 1, C = C0 + c - 1;
    float4 v0, v1, v2, v3;
    float av;
    unsigned char lf = 0;
    if ((unsigned)R < NH && (unsigned)C < NW) {
      const size_t P = ((size_t)bb * NH + R) * NW + C;
      const float* s = xprev + P * CHN;
      v0 = *(const float4*)(s);
      v1 = *(const float4*)(s + 4);
      v2 = *(const float4*)(s + 8);
      v3 = *(const float4*)(s + 12);
      if (STAGE_MASK) {
        float pool = -1e30f;
#pragma unroll
        for (int dr = 0; dr < 3; ++dr)
#pragma unroll
          for (int dc = 0; dc < 3; ++dc)
            pool = fmaxf(pool, aT2[(r + dr) * AW2 + (c + dc)]);
        lf = ((plIn[P] != 0) && (pool > 0.1f)) ? (unsigned char)1 : (unsigned char)0;
        const float m = (float)lf;
        v0.x *= m; v0.y *= m; v0.z *= m; v0.w *= m;
        v1.x *= m; v1.y *= m; v1.z *= m; v1.w *= m;
        v2.x *= m; v2.y *= m; v2.z *= m; v2.w *= m;
        v3.x *= m; v3.y *= m; v3.z *= m; v3.w *= m;
      } else {
        lf = 1;
      }
      av = v0.w;                            // exact f32 (masked) alpha
    } else {
      v0 = v1 = v2 = v3 = (float4){0.f, 0.f, 0.f, 0.f};
      av = -1e30f;
    }
    i32x4 u;
    u[0] = (int)pk2(v0.x, v0.y); u[1] = (int)pk2(v0.z, v0.w);
    u[2] = (int)pk2(v1.x, v1.y); u[3] = (int)pk2(v1.z, v1.w);
    *(i32x4*)&xT[h * CHN] = u;
    u[0] = (int)pk2(v2.x, v2.y); u[1] = (int)pk2(v2.z, v2.w);
    u[2] = (int)pk2(v3.x, v3.y); u[3] = (int)pk2(v3.z, v3.w);
    *(i32x4*)&xT[h * CHN + 8] = u;
    aT[h] = av;
    lifeB[h] = lf;
  }

  // ---- fire mask ----
  const int p = (bb * NH + R0 + w) * NW + C0 + l;
  unsigned long long fmask;
  {
    unsigned b1_, b2_;
    threefry2x32(sk0, sk1, 0u, (unsigned)p, b1_, b2_);
    fmask = __ballot(((b1_ ^ b2_) & 0x80000000u) == 0u);
  }

  __syncthreads();   // xT/aT/lifeB/W0s visible

  // ---- pre_life of the STAGED (masked) x -> plOut ----
  {
    float am = -1e30f;
#pragma unroll
    for (int dr = 0; dr < 3; ++dr)
#pragma unroll
      for (int dc = 0; dc < 3; ++dc)
        am = fmaxf(am, aT[(w + dr) * HW2 + (l + dc)]);
    plOut[p] = (am > 0.1f) ? (unsigned char)1 : (unsigned char)0;
  }

  // ---- build Yf fragments directly from xT (r19-verified) ----
  const bf16x8 zero8 = {};
  bf16x8 one8 = {};
  one8[0] = (short)0x3F80;
  const int choff = (lg & 1) << 3;
  const bool gH = (lg >= 2);
  const int sA = gH ? HW2 * CHN : CHN;
  const int sB = gH ? CHN : HW2 * CHN;

  bf16x8 Yf[4][2];
#pragma unroll
  for (int m = 0; m < 4; ++m) {
    const int q = (m << 4) + lc;
    const int base = ((w + 1) * HW2 + (q + 1)) * CHN + choff;
    const bf16x8 raw = *(const bf16x8*)&xT[base];
    const i32x4 M0 = *(const i32x4*)&xT[base - sA - sB];
    const i32x4 M1 = *(const i32x4*)&xT[base - sA];
    const i32x4 M2 = *(const i32x4*)&xT[base - sA + sB];
    const i32x4 P0 = *(const i32x4*)&xT[base + sA - sB];
    const i32x4 P1 = *(const i32x4*)&xT[base + sA];
    const i32x4 P2 = *(const i32x4*)&xT[base + sA + sB];
    i32x4 res;
#pragma unroll
    for (int k = 0; k < 4; ++k) {
      const float pl_ = fmaf(2.f, bflo(P1[k]), bflo(P0[k])) + bflo(P2[k]);
      const float ml_ = fmaf(2.f, bflo(M1[k]), bflo(M0[k])) + bflo(M2[k]);
      const float ph_ = fmaf(2.f, bfhi(P1[k]), bfhi(P0[k])) + bfhi(P2[k]);
      const float mh_ = fmaf(2.f, bfhi(M1[k]), bfhi(M0[k])) + bfhi(M2[k]);
      res[k] = (int)pk2((pl_ - ml_) * 0.125f, (ph_ - mh_) * 0.125f);
    }
    const bf16x8 st = __builtin_bit_cast(bf16x8, res);
    Yf[m][0] = gH ? st : raw;
    Yf[m][1] = gH ? ((lg == 2) ? one8 : zero8) : st;
  }

  // ---- W1 A-fragments from global ----
  bf16x8 W1f[4];
#pragma unroll
  for (int kt = 0; kt < 4; ++kt) {
    const float* src = &W1g[lc * HID + kt * 32 + (lg << 3)];
    W1f[kt] = cvt8(*(const float4*)(src), *(const float4*)(src + 4));
  }

  // T14: prefetch masked exact-f32 residual
  float4 xpre[4];
#pragma unroll
  for (int m = 0; m < 4; ++m) {
    const int q = (m << 4) + lc;
    const size_t P = ((size_t)bb * NH + R0 + w) * NW + C0 + q;
    float4 xc = *(const float4*)&xprev[P * CHN + (lg << 2)];
    const float ml = (float)lifeB[(w + 1) * HW2 + (q + 1)];
    xc.x *= ml; xc.y *= ml; xc.z *= ml; xc.w *= ml;
    xpre[m] = xc;
  }

  f32x4 dxacc[4];
#pragma unroll
  for (int m = 0; m < 4; ++m) dxacc[m] = (f32x4){0.f, 0.f, 0.f, 0.f};

#pragma unroll
  for (int kt_o = 0; kt_o < 4; ++kt_o) {
    bf16x8 Wf0[2], Wf1[2];
#pragma unroll
    for (int th = 0; th < 2; ++th) {
      const int row = ((((kt_o << 1) + th) << 4) + lc) * WSTR;
      Wf0[th] = *(const bf16x8*)&W0s[row + (lg << 3)];
      Wf1[th] = (lg < 3) ? *(const bf16x8*)&W0s[row + 32 + (lg << 3)] : zero8;
    }
#pragma unroll
    for (int m = 0; m < 4; ++m) {
      f32x4 a0 = __builtin_amdgcn_mfma_f32_16x16x32_bf16(
          Wf0[0], Yf[m][0], (f32x4){0.f, 0.f, 0.f, 0.f}, 0, 0, 0);
      a0 = __builtin_amdgcn_mfma_f32_16x16x32_bf16(Wf1[0], Yf[m][1], a0, 0, 0, 0);
      f32x4 a1 = __builtin_amdgcn_mfma_f32_16x16x32_bf16(
          Wf0[1], Yf[m][0], (f32x4){0.f, 0.f, 0.f, 0.f}, 0, 0, 0);
      a1 = __builtin_amdgcn_mfma_f32_16x16x32_bf16(Wf1[1], Yf[m][1], a1, 0, 0, 0);
      unsigned xa = pk2(fmaxf(a0[0], 0.f), fmaxf(a0[1], 0.f));
      unsigned xb = pk2(fmaxf(a0[2], 0.f), fmaxf(a0[3], 0.f));
      unsigned ya = pk2(fmaxf(a1[0], 0.f), fmaxf(a1[1], 0.f));
      unsigned yb = pk2(fmaxf(a1[2], 0.f), fmaxf(a1[3], 0.f));
      asm("v_permlane32_swap_b32 %0, %1" : "+v"(xa), "+v"(ya));
      asm("v_permlane32_swap_b32 %0, %1" : "+v"(xb), "+v"(yb));
      asm("v_permlane16_swap_b32 %0, %1" : "+v"(xa), "+v"(ya));
      asm("v_permlane16_swap_b32 %0, %1" : "+v"(xb), "+v"(yb));
      i32x4 bfr;
      bfr[0] = (int)xa; bfr[1] = (int)xb; bfr[2] = (int)ya; bfr[3] = (int)yb;
      dxacc[m] = __builtin_amdgcn_mfma_f32_16x16x32_bf16(
          W1f[kt_o], __builtin_bit_cast(bf16x8, bfr), dxacc[m], 0, 0, 0);
    }
  }

  // ---- epilogue: xmid = staged_x + dx*fire ----
#pragma unroll
  for (int m = 0; m < 4; ++m) {
    const int q = (m << 4) + lc;
    const size_t P = ((size_t)bb * NH + R0 + w) * NW + C0 + q;
    const float f = (float)((fmask >> q) & 1ull);
    float4 xm;
    xm.x = fmaf(dxacc[m][0], f, xpre[m].x);
    xm.y = fmaf(dxacc[m][1], f, xpre[m].y);
    xm.z = fmaf(dxacc[m][2], f, xpre[m].z);
    xm.w = fmaf(dxacc[m][3], f, xpre[m].w);
    *(float4*)&xmid[P * CHN + (lg << 2)] = xm;
  }
}

__global__ __launch_bounds__(TPB, 2) void ca_step_a(
    const float* __restrict__ xin,
    const float* __restrict__ W0g, const float* __restrict__ b0g,
    const float* __restrict__ W1g,
    float* __restrict__ xmid, unsigned char* __restrict__ plOut,
    unsigned sk0, unsigned sk1)
{
  __shared__ __align__(16) short W0s[128 * WSTR];
  __shared__ __align__(16) short xT[HH2 * HW2 * CHN];
  __shared__ float aT[HH2 * HW2];
  __shared__ unsigned char lifeB[HH2 * HW2];
  ca_core<0>(xin, nullptr, W0g, b0g, W1g, xmid, plOut, sk0, sk1,
             W0s, xT, aT, nullptr, lifeB);
}

__global__ __launch_bounds__(TPB, 2) void ca_step_f(
    const float* __restrict__ xprev,
    const unsigned char* __restrict__ plIn,
    const float* __restrict__ W0g, const float* __restrict__ b0g,
    const float* __restrict__ W1g,
    float* __restrict__ xmid, unsigned char* __restrict__ plOut,
    unsigned sk0, unsigned sk1)
{
  __shared__ __align__(16) short W0s[128 * WSTR];
  __shared__ __align__(16) short xT[HH2 * HW2 * CHN];
  __shared__ float aT[HH2 * HW2];
  __shared__ float aT2[AH2 * AW2];
  __shared__ unsigned char lifeB[HH2 * HW2];
  ca_core<1>(xprev, plIn, W0g, b0g, W1g, xmid, plOut, sk0, sk1,
             W0s, xT, aT, aT2, lifeB);
}

// Final masking: x_out = xmid * (plIn & pool3x3(xmid alpha) > 0.1)
__global__ __launch_bounds__(TPB) void ca_step_b(
    const float* __restrict__ xmid,
    const unsigned char* __restrict__ plIn,
    float* __restrict__ xout)
{
  const int p = blockIdx.x * TPB + threadIdx.x;
  const int j = p & (NW - 1);
  const int i = (p >> 7) & (NH - 1);
  float pmax = -1e30f;
#pragma unroll
  for (int dh = 0; dh < 3; ++dh) {
#pragma unroll
    for (int dw = 0; dw < 3; ++dw) {
      const int ii = i + dh - 1, jj = j + dw - 1;
      if ((unsigned)ii < NH && (unsigned)jj < NW)
        pmax = fmaxf(pmax, xmid[((size_t)p + (dh - 1) * NW + (dw - 1)) * CHN + 3]);
    }
  }
  const float m = ((pmax > 0.1f) && (plIn[p] != 0)) ? 1.f : 0.f;
  const float* src = xmid + (size_t)p * CHN;
  float4 a = *(const float4*)(src);
  float4 b = *(const float4*)(src + 4);
  float4 c = *(const float4*)(src + 8);
  float4 d = *(const float4*)(src + 12);
  a.x *= m; a.y *= m; a.z *= m; a.w *= m;
  b.x *= m; b.y *= m; b.z *= m; b.w *= m;
  c.x *= m; c.y *= m; c.z *= m; c.w *= m;
  d.x *= m; d.y *= m; d.z *= m; d.w *= m;
  float* dst = xout + (size_t)p * CHN;
  *(float4*)(dst)      = a;
  *(float4*)(dst + 4)  = b;
  *(float4*)(dst + 8)  = c;
  *(float4*)(dst + 12) = d;
}

extern "C" void kernel_launch(void* const* d_in, const int* in_sizes, int n_in,
                              void* d_out, int out_size, void* d_ws, size_t ws_size,
                              hipStream_t stream) {
  const float* x  = (const float*)d_in[0];
  const float* W0 = (const float*)d_in[1];
  const float* b0 = (const float*)d_in[2];
  const float* W1 = (const float*)d_in[3];
  float* out = (float*)d_out;

  char* ws = (char*)d_ws;
  float* X = (float*)ws;                                        // NPIX*16 f32
  unsigned char* pl0 = (unsigned char*)(ws + (size_t)NPIX * CHN * 4);
  unsigned char* pl1 = pl0 + NPIX;

  const dim3 grid(NPIX / TPB), block(TPB);
  unsigned k0[4], k1[4];
  for (int s = 0; s < 4; ++s) threefry2x32(0u, 42u, 0u, (unsigned)s, k0[s], k1[s]);

  // A(x)->out,pl0 ; A'(out)->X,pl1 ; A'(X)->out,pl0 ; A'(out)->X,pl1 ; B(X,pl1)->out
  ca_step_a<<<grid, block, 0, stream>>>(x, W0, b0, W1, out, pl0, k0[0], k1[0]);
  ca_step_f<<<grid, block, 0, stream>>>(out, pl0, W0, b0, W1, X, pl1, k0[1], k1[1]);
  ca_step_f<<<grid, block, 0, stream>>>(X, pl1, W0, b0, W1, out, pl0, k0[2], k1[2]);
  ca_step_f<<<grid, block, 0, stream>>>(out, pl0, W0, b0, W1, X, pl1, k0[3], k1[3]);
  ca_step_b<<<grid, block, 0, stream>>>(X, pl1, out);
}

// Round 22
// 171.812 us; speedup vs baseline: 1.4834x; 1.1232x over previous
//
#include <hip/hip_runtime.h>

#define CHN 16
#define HID 128
#define NB 32
#define NH 128
#define NW 128
#define NPIX (NB*NH*NW)      // 524288
#define TPB 256
#define XW 66                // x-tile halo width
#define XH 10                // x-tile halo rows (8 computed + 2)
#define AW2 68               // alpha halo width (+2 each side)
#define AH2 12               // alpha halo rows
#define WSTR 56              // W0s row stride: 0..47=W0, 48=b0, 49..55=0

typedef __attribute__((ext_vector_type(8))) short bf16x8;
typedef __attribute__((ext_vector_type(4))) float f32x4;
typedef __attribute__((ext_vector_type(4))) int i32x4;

// JAX threefry2x32 (20 rounds). Verified vs Random123 test vectors.
__host__ __device__ inline void threefry2x32(unsigned k0, unsigned k1,
                                             unsigned x0, unsigned x1,
                                             unsigned &o0, unsigned &o1) {
  unsigned ks2 = 0x1BD11BDAu ^ k0 ^ k1;
  unsigned v0 = x0 + k0, v1 = x1 + k1;
#define TF_R(r) { v0 += v1; v1 = (v1 << (r)) | (v1 >> (32-(r))); v1 ^= v0; }
  TF_R(13) TF_R(15) TF_R(26) TF_R(6)
  v0 += k1;  v1 += ks2 + 1u;
  TF_R(17) TF_R(29) TF_R(16) TF_R(24)
  v0 += ks2; v1 += k0 + 2u;
  TF_R(13) TF_R(15) TF_R(26) TF_R(6)
  v0 += k0;  v1 += k1 + 3u;
  TF_R(17) TF_R(29) TF_R(16) TF_R(24)
  v0 += k1;  v1 += ks2 + 4u;
  TF_R(13) TF_R(15) TF_R(26) TF_R(6)
  v0 += ks2; v1 += k0 + 5u;
#undef TF_R
  o0 = v0; o1 = v1;
}

__device__ inline unsigned short f2bf(float f) {
  return __builtin_bit_cast(unsigned short, (__bf16)f);
}
__device__ inline unsigned pk2(float lo, float hi) {
  return (unsigned)f2bf(lo) | ((unsigned)f2bf(hi) << 16);
}
__device__ inline bf16x8 cvt8(float4 a, float4 b) {
  i32x4 r;
  r[0] = (int)pk2(a.x, a.y); r[1] = (int)pk2(a.z, a.w);
  r[2] = (int)pk2(b.x, b.y); r[3] = (int)pk2(b.z, b.w);
  return __builtin_bit_cast(bf16x8, r);
}
__device__ inline float bflo(int u) {
  return __builtin_bit_cast(float, (unsigned)u << 16);
}
__device__ inline float bfhi(int u) {
  return __builtin_bit_cast(float, (unsigned)u & 0xFFFF0000u);
}

// ---- shared core (r21-verified numerics, 8-row tile, 2 sequential halves) ----
// STAGE_MASK=1 fuses previous step's post-life mask into staging.
template <int STAGE_MASK>
__device__ __forceinline__ void ca_core(
    const float* __restrict__ xprev,
    const unsigned char* __restrict__ plIn,
    const float* __restrict__ W0g,
    const float* __restrict__ b0g,
    const float* __restrict__ W1g,
    float* __restrict__ xmid,
    unsigned char* __restrict__ plOut,
    unsigned sk0, unsigned sk1,
    short* W0s, short* xT, float* aT, float* aT2, unsigned char* lifeB)
{
  const int tid = threadIdx.x;
  const int w = tid >> 6, l = tid & 63;
  const int lc = l & 15, lg = l >> 4;

  const int bb = blockIdx.x >> 5;           // batch
  const int t5 = blockIdx.x & 31;
  const int R0 = (t5 >> 1) << 3;            // tile row base (8 rows)
  const int C0 = (t5 & 1) << 6;             // tile col base (64 cols)

  // ---- stage W0 (f32->bf16) + bias col 48 + zero pad ----
  {
    const int o = tid >> 1;
    if ((tid & 1) == 0) {
#pragma unroll
      for (int k = 0; k < 24; k += 2)
        *(unsigned*)&W0s[o * WSTR + k] = pk2(W0g[o * 48 + k], W0g[o * 48 + k + 1]);
    } else {
#pragma unroll
      for (int k = 24; k < 48; k += 2)
        *(unsigned*)&W0s[o * WSTR + k] = pk2(W0g[o * 48 + k], W0g[o * 48 + k + 1]);
      *(unsigned*)&W0s[o * WSTR + 48] = (unsigned)f2bf(b0g[o]);
      *(unsigned*)&W0s[o * WSTR + 50] = 0u;
      *(unsigned*)&W0s[o * WSTR + 52] = 0u;
      *(unsigned*)&W0s[o * WSTR + 54] = 0u;
    }
  }

  if (STAGE_MASK) {
    // stage raw xprev alpha (+2 halo) for the fused post-life pool
    for (int h2 = tid; h2 < AH2 * AW2; h2 += TPB) {
      const int r2 = h2 / AW2, c2 = h2 - r2 * AW2;
      const int Rg = R0 + r2 - 2, Cg = C0 + c2 - 2;
      aT2[h2] = ((unsigned)Rg < NH && (unsigned)Cg < NW)
          ? xprev[(((size_t)bb * NH + Rg) * NW + Cg) * CHN + 3] : -1e30f;
    }
    __syncthreads();
  }

  // ---- stage x halo tile (bf16, masked if STAGE_MASK) + alpha tile (f32) ----
  for (int h = tid; h < XH * XW; h += TPB) {
    const int r = h / XW, c = h - r * XW;
    const int R = R0 + r - 1, C = C0 + c - 1;
    float4 v0, v1, v2, v3;
    float av;
    unsigned char lf = 0;
    if ((unsigned)R < NH && (unsigned)C < NW) {
      const size_t P = ((size_t)bb * NH + R) * NW + C;
      const float* s = xprev + P * CHN;
      v0 = *(const float4*)(s);
      v1 = *(const float4*)(s + 4);
      v2 = *(const float4*)(s + 8);
      v3 = *(const float4*)(s + 12);
      if (STAGE_MASK) {
        float pool = -1e30f;
#pragma unroll
        for (int dr = 0; dr < 3; ++dr)
#pragma unroll
          for (int dc = 0; dc < 3; ++dc)
            pool = fmaxf(pool, aT2[(r + dr) * AW2 + (c + dc)]);
        lf = ((plIn[P] != 0) && (pool > 0.1f)) ? (unsigned char)1 : (unsigned char)0;
        const float m = (float)lf;
        v0.x *= m; v0.y *= m; v0.z *= m; v0.w *= m;
        v1.x *= m; v1.y *= m; v1.z *= m; v1.w *= m;
        v2.x *= m; v2.y *= m; v2.z *= m; v2.w *= m;
        v3.x *= m; v3.y *= m; v3.z *= m; v3.w *= m;
      } else {
        lf = 1;
      }
      av = v0.w;
    } else {
      v0 = v1 = v2 = v3 = (float4){0.f, 0.f, 0.f, 0.f};
      av = -1e30f;
    }
    i32x4 u;
    u[0] = (int)pk2(v0.x, v0.y); u[1] = (int)pk2(v0.z, v0.w);
    u[2] = (int)pk2(v1.x, v1.y); u[3] = (int)pk2(v1.z, v1.w);
    *(i32x4*)&xT[h * CHN] = u;
    u[0] = (int)pk2(v2.x, v2.y); u[1] = (int)pk2(v2.z, v2.w);
    u[2] = (int)pk2(v3.x, v3.y); u[3] = (int)pk2(v3.z, v3.w);
    *(i32x4*)&xT[h * CHN + 8] = u;
    aT[h] = av;
    lifeB[h] = lf;
  }

  // ---- W1 A-fragments (once per block) ----
  bf16x8 W1f[4];
#pragma unroll
  for (int kt = 0; kt < 4; ++kt) {
    const float* src = &W1g[lc * HID + kt * 32 + (lg << 3)];
    W1f[kt] = cvt8(*(const float4*)(src), *(const float4*)(src + 4));
  }

  __syncthreads();   // xT/aT/lifeB/W0s visible

  const bf16x8 zero8 = {};
  bf16x8 one8 = {};
  one8[0] = (short)0x3F80;
  const int choff = (lg & 1) << 3;
  const bool gH = (lg >= 2);
  const int sA = gH ? XW * CHN : CHN;
  const int sB = gH ? CHN : XW * CHN;

  // ================= two sequential 4-row halves =================
#pragma unroll
  for (int hf = 0; hf < 2; ++hf) {
    const int rw = (hf << 2) + w;                    // tile row (0..7) this wave
    const int p = (bb * NH + R0 + rw) * NW + C0 + l; // own pixel for fire/plOut

    unsigned long long fmask;
    {
      unsigned b1_, b2_;
      threefry2x32(sk0, sk1, 0u, (unsigned)p, b1_, b2_);
      fmask = __ballot(((b1_ ^ b2_) & 0x80000000u) == 0u);
    }

    // pre_life of staged (masked) x -> plOut
    {
      float am = -1e30f;
#pragma unroll
      for (int dr = 0; dr < 3; ++dr)
#pragma unroll
        for (int dc = 0; dc < 3; ++dc)
          am = fmaxf(am, aT[(rw + dr) * XW + (l + dc)]);
      plOut[p] = (am > 0.1f) ? (unsigned char)1 : (unsigned char)0;
    }

    // Yf fragments from xT (r19/r21-verified stencil)
    bf16x8 Yf[4][2];
#pragma unroll
    for (int m = 0; m < 4; ++m) {
      const int q = (m << 4) + lc;
      const int base = ((rw + 1) * XW + (q + 1)) * CHN + choff;
      const bf16x8 raw = *(const bf16x8*)&xT[base];
      const i32x4 M0 = *(const i32x4*)&xT[base - sA - sB];
      const i32x4 M1 = *(const i32x4*)&xT[base - sA];
      const i32x4 M2 = *(const i32x4*)&xT[base - sA + sB];
      const i32x4 P0 = *(const i32x4*)&xT[base + sA - sB];
      const i32x4 P1 = *(const i32x4*)&xT[base + sA];
      const i32x4 P2 = *(const i32x4*)&xT[base + sA + sB];
      i32x4 res;
#pragma unroll
      for (int k = 0; k < 4; ++k) {
        const float pl_ = fmaf(2.f, bflo(P1[k]), bflo(P0[k])) + bflo(P2[k]);
        const float ml_ = fmaf(2.f, bflo(M1[k]), bflo(M0[k])) + bflo(M2[k]);
        const float ph_ = fmaf(2.f, bfhi(P1[k]), bfhi(P0[k])) + bfhi(P2[k]);
        const float mh_ = fmaf(2.f, bfhi(M1[k]), bfhi(M0[k])) + bfhi(M2[k]);
        res[k] = (int)pk2((pl_ - ml_) * 0.125f, (ph_ - mh_) * 0.125f);
      }
      const bf16x8 st = __builtin_bit_cast(bf16x8, res);
      Yf[m][0] = gH ? st : raw;
      Yf[m][1] = gH ? ((lg == 2) ? one8 : zero8) : st;
    }

    // T14 prefetch: masked exact-f32 residual
    float4 xpre[4];
#pragma unroll
    for (int m = 0; m < 4; ++m) {
      const int q = (m << 4) + lc;
      const size_t P = ((size_t)bb * NH + R0 + rw) * NW + C0 + q;
      float4 xc = *(const float4*)&xprev[P * CHN + (lg << 2)];
      const float ml = (float)lifeB[(rw + 1) * XW + (q + 1)];
      xc.x *= ml; xc.y *= ml; xc.z *= ml; xc.w *= ml;
      xpre[m] = xc;
    }

    f32x4 dxacc[4];
#pragma unroll
    for (int m = 0; m < 4; ++m) dxacc[m] = (f32x4){0.f, 0.f, 0.f, 0.f};

#pragma unroll
    for (int kt_o = 0; kt_o < 4; ++kt_o) {
      bf16x8 Wf0[2], Wf1[2];
#pragma unroll
      for (int th = 0; th < 2; ++th) {
        const int row = ((((kt_o << 1) + th) << 4) + lc) * WSTR;
        Wf0[th] = *(const bf16x8*)&W0s[row + (lg << 3)];
        Wf1[th] = (lg < 3) ? *(const bf16x8*)&W0s[row + 32 + (lg << 3)] : zero8;
      }
#pragma unroll
      for (int m = 0; m < 4; ++m) {
        f32x4 a0 = __builtin_amdgcn_mfma_f32_16x16x32_bf16(
            Wf0[0], Yf[m][0], (f32x4){0.f, 0.f, 0.f, 0.f}, 0, 0, 0);
        a0 = __builtin_amdgcn_mfma_f32_16x16x32_bf16(Wf1[0], Yf[m][1], a0, 0, 0, 0);
        f32x4 a1 = __builtin_amdgcn_mfma_f32_16x16x32_bf16(
            Wf0[1], Yf[m][0], (f32x4){0.f, 0.f, 0.f, 0.f}, 0, 0, 0);
        a1 = __builtin_amdgcn_mfma_f32_16x16x32_bf16(Wf1[1], Yf[m][1], a1, 0, 0, 0);
        unsigned xa = pk2(fmaxf(a0[0], 0.f), fmaxf(a0[1], 0.f));
        unsigned xb = pk2(fmaxf(a0[2], 0.f), fmaxf(a0[3], 0.f));
        unsigned ya = pk2(fmaxf(a1[0], 0.f), fmaxf(a1[1], 0.f));
        unsigned yb = pk2(fmaxf(a1[2], 0.f), fmaxf(a1[3], 0.f));
        asm("v_permlane32_swap_b32 %0, %1" : "+v"(xa), "+v"(ya));
        asm("v_permlane32_swap_b32 %0, %1" : "+v"(xb), "+v"(yb));
        asm("v_permlane16_swap_b32 %0, %1" : "+v"(xa), "+v"(ya));
        asm("v_permlane16_swap_b32 %0, %1" : "+v"(xb), "+v"(yb));
        i32x4 bfr;
        bfr[0] = (int)xa; bfr[1] = (int)xb; bfr[2] = (int)ya; bfr[3] = (int)yb;
        dxacc[m] = __builtin_amdgcn_mfma_f32_16x16x32_bf16(
            W1f[kt_o], __builtin_bit_cast(bf16x8, bfr), dxacc[m], 0, 0, 0);
      }
    }

    // epilogue: xmid = staged_x + dx*fire
#pragma unroll
    for (int m = 0; m < 4; ++m) {
      const int q = (m << 4) + lc;
      const size_t P = ((size_t)bb * NH + R0 + rw) * NW + C0 + q;
      const float f = (float)((fmask >> q) & 1ull);
      float4 xm;
      xm.x = fmaf(dxacc[m][0], f, xpre[m].x);
      xm.y = fmaf(dxacc[m][1], f, xpre[m].y);
      xm.z = fmaf(dxacc[m][2], f, xpre[m].z);
      xm.w = fmaf(dxacc[m][3], f, xpre[m].w);
      *(float4*)&xmid[P * CHN + (lg << 2)] = xm;
    }
  }
}

__global__ __launch_bounds__(TPB, 2) void ca_step_a(
    const float* __restrict__ xin,
    const float* __restrict__ W0g, const float* __restrict__ b0g,
    const float* __restrict__ W1g,
    float* __restrict__ xmid, unsigned char* __restrict__ plOut,
    unsigned sk0, unsigned sk1)
{
  __shared__ __align__(16) short W0s[128 * WSTR];
  __shared__ __align__(16) short xT[XH * XW * CHN];
  __shared__ float aT[XH * XW];
  __shared__ unsigned char lifeB[XH * XW];
  ca_core<0>(xin, nullptr, W0g, b0g, W1g, xmid, plOut, sk0, sk1,
             W0s, xT, aT, nullptr, lifeB);
}

__global__ __launch_bounds__(TPB, 2) void ca_step_f(
    const float* __restrict__ xprev,
    const unsigned char* __restrict__ plIn,
    const float* __restrict__ W0g, const float* __restrict__ b0g,
    const float* __restrict__ W1g,
    float* __restrict__ xmid, unsigned char* __restrict__ plOut,
    unsigned sk0, unsigned sk1)
{
  __shared__ __align__(16) short W0s[128 * WSTR];
  __shared__ __align__(16) short xT[XH * XW * CHN];
  __shared__ float aT[XH * XW];
  __shared__ float aT2[AH2 * AW2];
  __shared__ unsigned char lifeB[XH * XW];
  ca_core<1>(xprev, plIn, W0g, b0g, W1g, xmid, plOut, sk0, sk1,
             W0s, xT, aT, aT2, lifeB);
}

// Final masking: x_out = xmid * (plIn & pool3x3(xmid alpha) > 0.1)
__global__ __launch_bounds__(TPB) void ca_step_b(
    const float* __restrict__ xmid,
    const unsigned char* __restrict__ plIn,
    float* __restrict__ xout)
{
  const int p = blockIdx.x * TPB + threadIdx.x;
  const int j = p & (NW - 1);
  const int i = (p >> 7) & (NH - 1);
  float pmax = -1e30f;
#pragma unroll
  for (int dh = 0; dh < 3; ++dh) {
#pragma unroll
    for (int dw = 0; dw < 3; ++dw) {
      const int ii = i + dh - 1, jj = j + dw - 1;
      if ((unsigned)ii < NH && (unsigned)jj < NW)
        pmax = fmaxf(pmax, xmid[((size_t)p + (dh - 1) * NW + (dw - 1)) * CHN + 3]);
    }
  }
  const float m = ((pmax > 0.1f) && (plIn[p] != 0)) ? 1.f : 0.f;
  const float* src = xmid + (size_t)p * CHN;
  float4 a = *(const float4*)(src);
  float4 b = *(const float4*)(src + 4);
  float4 c = *(const float4*)(src + 8);
  float4 d = *(const float4*)(src + 12);
  a.x *= m; a.y *= m; a.z *= m; a.w *= m;
  b.x *= m; b.y *= m; b.z *= m; b.w *= m;
  c.x *= m; c.y *= m; c.z *= m; c.w *= m;
  d.x *= m; d.y *= m; d.z *= m; d.w *= m;
  float* dst = xout + (size_t)p * CHN;
  *(float4*)(dst)      = a;
  *(float4*)(dst + 4)  = b;
  *(float4*)(dst + 8)  = c;
  *(float4*)(dst + 12) = d;
}

extern "C" void kernel_launch(void* const* d_in, const int* in_sizes, int n_in,
                              void* d_out, int out_size, void* d_ws, size_t ws_size,
                              hipStream_t stream) {
  const float* x  = (const float*)d_in[0];
  const float* W0 = (const float*)d_in[1];
  const float* b0 = (const float*)d_in[2];
  const float* W1 = (const float*)d_in[3];
  float* out = (float*)d_out;

  char* ws = (char*)d_ws;
  float* X = (float*)ws;                                        // NPIX*16 f32
  unsigned char* pl0 = (unsigned char*)(ws + (size_t)NPIX * CHN * 4);
  unsigned char* pl1 = pl0 + NPIX;

  const dim3 gridS(NPIX / 512), block(TPB);   // 8x64 tile = 512 px/block
  const dim3 gridB(NPIX / TPB);
  unsigned k0[4], k1[4];
  for (int s = 0; s < 4; ++s) threefry2x32(0u, 42u, 0u, (unsigned)s, k0[s], k1[s]);

  // A(x)->out,pl0 ; A'(out)->X,pl1 ; A'(X)->out,pl0 ; A'(out)->X,pl1 ; B(X,pl1)->out
  ca_step_a<<<gridS, block, 0, stream>>>(x, W0, b0, W1, out, pl0, k0[0], k1[0]);
  ca_step_f<<<gridS, block, 0, stream>>>(out, pl0, W0, b0, W1, X, pl1, k0[1], k1[1]);
  ca_step_f<<<gridS, block, 0, stream>>>(X, pl1, W0, b0, W1, out, pl0, k0[2], k1[2]);
  ca_step_f<<<gridS, block, 0, stream>>>(out, pl0, W0, b0, W1, X, pl1, k0[3], k1[3]);
  ca_step_b<<<gridB, block, 0, stream>>>(X, pl1, out);
}